// Round 16
// baseline (157.111 us; speedup 1.0000x reference)
//
#include <hip/hip_runtime.h>
#include <hip/hip_bf16.h>
#include <stdint.h>

// Problem constants
#define B_    64
#define N_    197
#define C_    768
#define H_    12
#define HD_   64
#define M_    (B_ * N_)     // 12608
#define MPAD  12672         // 99 * 128
#define KP_   224           // padded key-dim stride for V^T (global)
#define VS_   208           // V^T row stride in LDS (26 granules -> <=2-way)
#define LOG2E 1.44269504f
#define QSCALE_ (0.125f * LOG2E)   // 64^-0.5 folded with log2e (softmax uses exp2)

typedef unsigned short u16;
typedef __attribute__((ext_vector_type(8))) __bf16 bf16x8;
typedef __attribute__((ext_vector_type(4))) float  f32x4;

__device__ __forceinline__ u16 f2bf(float f) {
  union { float f; uint32_t u; } v; v.f = f;
  uint32_t r = (v.u + 0x7FFFu + ((v.u >> 16) & 1u)) >> 16;
  return (u16)r;
}
__device__ __forceinline__ float bf2f(u16 u) {
  union { uint32_t u; float f; } v; v.u = ((uint32_t)u) << 16;
  return v.f;
}

// bijective XCD-chunked swizzle (m204): consecutive wgids land on one XCD.
__device__ __forceinline__ int xcd_swz(int orig, int nwg) {
  int q = nwg >> 3, r = nwg & 7;
  int xcd = orig & 7, idx = orig >> 3;
  int base = (xcd < r) ? xcd * (q + 1) : r * (q + 1) + (xcd - r) * q;
  return base + idx;
}

// async global->LDS 16B copy. Dest must be wave-base + lane*16 (linear);
// NEVER mask individual lanes inside a staging wave (m104/m108 - the HW
// ignores per-lane dest addresses). R15's NaN was exactly that bug.
#define GLDS(g, l)                                                             \
  __builtin_amdgcn_global_load_lds(                                            \
      (const __attribute__((address_space(1))) void*)(g),                      \
      (__attribute__((address_space(3))) void*)(l), 16, 0, 0)

// --------------------------------------------------------------- fused prep
__device__ __forceinline__ uint4 cvt8(const float* __restrict__ p) {
  const float4* s4 = (const float4*)p;
  float4 a = s4[0], b = s4[1];
  uint4 o;
  o.x = (uint32_t)f2bf(a.x) | ((uint32_t)f2bf(a.y) << 16);
  o.y = (uint32_t)f2bf(a.z) | ((uint32_t)f2bf(a.w) << 16);
  o.z = (uint32_t)f2bf(b.x) | ((uint32_t)f2bf(b.y) << 16);
  o.w = (uint32_t)f2bf(b.z) | ((uint32_t)f2bf(b.w) << 16);
  return o;
}

__global__ __launch_bounds__(256) void k_prep(
    const float* __restrict__ x, const float* __restrict__ qkv_w,
    const float* __restrict__ proj_w, const float* __restrict__ rel,
    const int* __restrict__ idx,
    u16* __restrict__ x16, u16* __restrict__ wq16, u16* __restrict__ wp16,
    u16* __restrict__ bb16) {
  const int b = blockIdx.x, t = threadIdx.x;
  if (b < 4752) {
    int i = b * 256 + t;
    size_t e = (size_t)i * 8;
    uint4 o;
    if (e < (size_t)M_ * C_) o = cvt8(x + e);
    else { o.x = o.y = o.z = o.w = 0u; }
    *(uint4*)(x16 + e) = o;
  } else if (b < 5616) {
    int i = (b - 4752) * 256 + t;
    if (i < 221184) { size_t e = (size_t)i * 8; *(uint4*)(wq16 + e) = cvt8(qkv_w + e); }
  } else if (b < 5904) {
    int i = (b - 5616) * 256 + t;
    if (i < 73728) { size_t e = (size_t)i * 8; *(uint4*)(wp16 + e) = cvt8(proj_w + e); }
  } else {
    int j = b - 5904;                 // 0..1919
    int h = j / 160;
    int i = (j - h * 160) * 256 + t;
    if (i < 196 * 208) {
      int qi1 = i / 208, colk = i - qi1 * 208;
      float v = 0.f;
      if (colk >= 1 && colk <= 196)
        v = rel[h * 729 + idx[qi1 * 196 + (colk - 1)]] * LOG2E;
      bb16[(size_t)h * 196 * 208 + i] = f2bf(v);
    }
  }
}

// ------------------------------------------------------------- GEMM core
// BK=32 double-buffered 2-phase, 40 KB LDS -> higher residency than the
// 64 KB BK=64 version. LDS rows are 80 B (5 slots of 16 B); slots 0..3 hold
// granules 0..3, slot 4 is a bank-spread pad: it IS written (duplicate of
// granule 3 - full-wave linear dest, no lane masking) but never read.
// Read at row*80 + rowg*16: word index row*20+rowg*4 mod 32 -> 16 lanes land
// 2 per bank (free 2-way).
#define STAGE32(SM, buf, kt, Ab, Bb)                                           \
  do {                                                                         \
    char* As_ = (char*)(SM) + (buf) * 20480;                                   \
    char* Bs_ = As_ + 10240;                                                   \
    _Pragma("unroll") for (int r_ = 0; r_ < 3; ++r_) {                         \
      int c_ = r_ * 256 + t;                                                   \
      if (c_ < 640) {                                                          \
        int row_ = c_ / 5, j_ = c_ - row_ * 5;                                 \
        int jj_ = (j_ == 4) ? 3 : j_;                                          \
        GLDS((const char*)((Ab) + (size_t)row_ * 768 + (kt) * 32 + jj_ * 8),   \
             As_ + c_ * 16);                                                   \
        GLDS((const char*)((Bb) + (size_t)row_ * 768 + (kt) * 32 + jj_ * 8),   \
             Bs_ + c_ * 16);                                                   \
      }                                                                        \
    }                                                                          \
  } while (0)

#define GEMM_LOOP32(SM)                                                        \
  STAGE32(SM, 0, 0, Abase, Bbase);                                             \
  __syncthreads();                                                             \
  int cur = 0;                                                                 \
  for (int kt = 1; kt <= 24; ++kt) {                                           \
    if (kt < 24) STAGE32(SM, cur ^ 1, kt, Abase, Bbase);                       \
    const char* As_ = (const char*)(SM) + cur * 20480;                         \
    const char* Bs_ = As_ + 10240;                                             \
    bf16x8 af[4], bfr[4];                                                      \
    _Pragma("unroll") for (int mi = 0; mi < 4; ++mi) {                         \
      int row = wr + mi * 16 + col16;                                          \
      af[mi] = *(const bf16x8*)(As_ + row * 80 + rowg * 16);                   \
    }                                                                          \
    _Pragma("unroll") for (int ni = 0; ni < 4; ++ni) {                         \
      int row = wc + ni * 16 + col16;                                          \
      bfr[ni] = *(const bf16x8*)(Bs_ + row * 80 + rowg * 16);                  \
    }                                                                          \
    _Pragma("unroll") for (int mi = 0; mi < 4; ++mi)                           \
      _Pragma("unroll") for (int ni = 0; ni < 4; ++ni)                         \
        acc[mi][ni] = __builtin_amdgcn_mfma_f32_16x16x32_bf16(                 \
            af[mi], bfr[ni], acc[mi][ni], 0, 0, 0);                            \
    __syncthreads();                                                           \
    cur ^= 1;                                                                  \
  }

// ------------------------------------------------------------- qkv GEMM
__global__ __launch_bounds__(256) void k_gemm_qkv(
    const u16* __restrict__ A, const u16* __restrict__ Bt,
    const float* __restrict__ bias,
    u16* __restrict__ qb, u16* __restrict__ kb, u16* __restrict__ vtb) {
  __shared__ u16 SMEM[20480];               // 40960 B: 2 buf x (A 10240 + B 10240)
  const int t = threadIdx.x, lane = t & 63;
  const int w = t >> 6;
  const int wr = (w >> 1) * 64, wc = (w & 1) * 64;
  const int wg = xcd_swz(blockIdx.x, 99 * 18);
  const int tm = wg / 18, tn = wg % 18;
  const int rowg = lane >> 4, col16 = lane & 15;

  f32x4 acc[4][4] = {};
  const u16* Abase = A + (size_t)tm * 128 * 768;
  const u16* Bbase = Bt + (size_t)tn * 128 * 768;

  GEMM_LOOP32(SMEM)

  if (tn < 12) {
    u16* dst = (tn < 6) ? qb : kb;
    const float scl = (tn < 6) ? QSCALE_ : 1.f;
    const int colbase = tn * 128 - ((tn < 6) ? 0 : 768);
#pragma unroll
    for (int mi = 0; mi < 4; ++mi) {
#pragma unroll
      for (int r = 0; r < 4; ++r) {
        int gm = tm * 128 + wr + mi * 16 + rowg * 4 + r;
        if (gm >= M_) continue;
        int bb = gm / 197, nn = gm - bb * 197;
#pragma unroll
        for (int ni = 0; ni < 4; ++ni) {
          int n = wc + ni * 16 + col16;
          int rem = colbase + n;
          int hh = rem >> 6, hd = rem & 63;
          float v = (acc[mi][ni][r] + bias[tn * 128 + n]) * scl;
          dst[((size_t)(bb * 12 + hh) * 197 + nn) * 64 + hd] = f2bf(v);
        }
      }
    }
  } else {
    // v block: transpose through LDS ([128][128] u16 = 32768 B <= 40960 B),
    // XOR-swizzled, then m-coalesced readback into V^T.
    u16* T = SMEM;
    __syncthreads();
#pragma unroll
    for (int mi = 0; mi < 4; ++mi)
#pragma unroll
      for (int r = 0; r < 4; ++r) {
        int m = wr + mi * 16 + rowg * 4 + r;
#pragma unroll
        for (int ni = 0; ni < 4; ++ni) {
          int n = wc + ni * 16 + col16;
          float v = acc[mi][ni][r] + bias[tn * 128 + n];
          T[n * 128 + (m ^ ((n & 7) << 3))] = f2bf(v);
        }
      }
    __syncthreads();
    const int l = t & 15, g = t >> 4;
#pragma unroll
    for (int p = 0; p < 8; ++p) {
      int n = p * 16 + g;
      int rem = tn * 128 + n - 1536;
      int hh = rem >> 6, hd = rem & 63;
#pragma unroll
      for (int i = 0; i < 8; ++i) {
        int m = i * 16 + l;
        int gm = tm * 128 + m;
        if (gm >= M_) continue;
        int bb = gm / 197, nn = gm - bb * 197;
        u16 val = T[n * 128 + (m ^ ((n & 7) << 3))];
        vtb[((size_t)((bb * 12 + hh) * 64 + hd)) * KP_ + nn] = val;
      }
    }
  }
}

// ------------------------------------------------------------- attention
// R13 structure: one (b,h) per block, K/V staged once (62 KB LDS), 8 waves
// consume 13 q-tiles barrier-free.
__global__ __launch_bounds__(512) void k_attn(
    const u16* __restrict__ qb, const u16* __restrict__ kb,
    const u16* __restrict__ vtb, const u16* __restrict__ biasb,
    u16* __restrict__ ob) {
  __shared__ u16 Ks[208 * 64];              // 26.0 KB
  __shared__ u16 Vs[64 * VS_];              // 26.0 KB
  __shared__ u16 Ps[8][16 * 40];            // 10.0 KB   -> total 62 KB
  const int t = threadIdx.x, lane = t & 63, w = t >> 6;
  const int bh = xcd_swz(blockIdx.x, 768);
  const int hh = bh % 12, bb = bh / 12;
  const int rowg = lane >> 4, col16 = lane & 15;
  const u16* kbase = kb + (size_t)bh * 197 * 64;
  const u16* qbase = qb + (size_t)bh * 197 * 64;
  const u16* vbase = vtb + (size_t)bh * 64 * KP_;

#pragma unroll
  for (int i = 0; i < 4; ++i) {
    int c = i * 512 + t;
    if (c < 1664) {
      int row = c >> 3, sl = c & 7, p = sl ^ (row & 7);
      GLDS((const char*)(kbase + row * 64 + p * 8), (char*)Ks + c * 16);
    }
  }
#pragma unroll
  for (int i = 0; i < 4; ++i) {
    int c = i * 512 + t;
    if (c < 1664) {
      int vrow = c / 26, g = c - vrow * 26;
      GLDS((const char*)(vbase + vrow * 224 + g * 8), (char*)Vs + c * 16);
    }
  }
  asm volatile("s_waitcnt vmcnt(0)" ::: "memory");
  __syncthreads();
#pragma unroll
  for (int i = 0; i < 2; ++i) {
    int idx = i * 512 + t;
    if (idx < 704) {
      int r2 = idx / 11, e = idx - r2 * 11;
      Vs[r2 * VS_ + 197 + e] = 0;
    }
  }
  __syncthreads();

  for (int pass = 0; pass < 2; ++pass) {
    const int qt = w + pass * 8;
    if (qt > 12) break;
    const int q0 = qt * 16;
    const int qi = q0 + col16;

    bf16x8 qa0 = *(const bf16x8*)(qbase + (size_t)qi * 64 + rowg * 8);
    bf16x8 qa1 = *(const bf16x8*)(qbase + (size_t)qi * 64 + 32 + rowg * 8);

    const bool doB = (qi >= 1) && (qi < 197);
    const float bm = doB ? 1.f : 0.f;
    const u16* brow = biasb + ((size_t)hh * 196 + (doB ? qi - 1 : 0)) * 208;

    f32x4 sv[13];
    float mx = -1e38f;
#pragma unroll
    for (int nj = 0; nj < 13; ++nj) {
      int rk = nj * 16 + col16;
      const char* kp = (const char*)Ks + rk * 128;
      bf16x8 a0 = *(const bf16x8*)(kp + ((rowg ^ (rk & 7)) * 16));
      bf16x8 a1 = *(const bf16x8*)(kp + (((rowg + 4) ^ (rk & 7)) * 16));
      f32x4 s = {0.f, 0.f, 0.f, 0.f};
      s = __builtin_amdgcn_mfma_f32_16x16x32_bf16(a0, qa0, s, 0, 0, 0);
      s = __builtin_amdgcn_mfma_f32_16x16x32_bf16(a1, qa1, s, 0, 0, 0);
      ushort4 bu = *(const ushort4*)(brow + nj * 16 + rowg * 4);
      float s0 = fmaf(bf2f(bu.x), bm, s[0]);
      float s1 = fmaf(bf2f(bu.y), bm, s[1]);
      float s2 = fmaf(bf2f(bu.z), bm, s[2]);
      float s3 = fmaf(bf2f(bu.w), bm, s[3]);
      if (nj == 12) {
        if (192 + rowg * 4 + 0 >= 197) s0 = -1e38f;
        if (192 + rowg * 4 + 1 >= 197) s1 = -1e38f;
        if (192 + rowg * 4 + 2 >= 197) s2 = -1e38f;
        if (192 + rowg * 4 + 3 >= 197) s3 = -1e38f;
      }
      sv[nj][0] = s0; sv[nj][1] = s1; sv[nj][2] = s2; sv[nj][3] = s3;
      mx = fmaxf(fmaxf(mx, fmaxf(s0, s1)), fmaxf(s2, s3));
    }
    mx = fmaxf(mx, __shfl_xor(mx, 16));
    mx = fmaxf(mx, __shfl_xor(mx, 32));

    float sm = 0.f;
#pragma unroll
    for (int nj = 0; nj < 13; ++nj)
#pragma unroll
      for (int r = 0; r < 4; ++r) {
        float p = exp2f(sv[nj][r] - mx);
        sv[nj][r] = p;
        sm += p;
      }
    sm += __shfl_xor(sm, 16);
    sm += __shfl_xor(sm, 32);
    float inv = 1.f / sm;

    uint2 pk[13];
#pragma unroll
    for (int nj = 0; nj < 13; ++nj) {
      float n0 = sv[nj][0] * inv, n1 = sv[nj][1] * inv;
      float n2 = sv[nj][2] * inv, n3 = sv[nj][3] * inv;
      uint32_t lo, hi;
      asm("v_cvt_pk_bf16_f32 %0, %1, %2" : "=v"(lo) : "v"(n0), "v"(n1));
      asm("v_cvt_pk_bf16_f32 %0, %1, %2" : "=v"(hi) : "v"(n2), "v"(n3));
      pk[nj].x = lo; pk[nj].y = hi;
    }

    u16* pw = Ps[w];
    uint2 z2; z2.x = 0u; z2.y = 0u;
    union { uint32_t u[4]; bf16x8 v; } zz;
    zz.u[0] = zz.u[1] = zz.u[2] = zz.u[3] = 0u;
    const bf16x8 z8 = zz.v;

    f32x4 oa[4] = {};
#pragma unroll
    for (int c = 0; c < 7; ++c) {
      *(uint2*)(pw + col16 * 40 + rowg * 4) = pk[2 * c];
      *(uint2*)(pw + col16 * 40 + 16 + rowg * 4) = (c == 6) ? z2 : pk[2 * c + 1];
      bf16x8 pa = *(const bf16x8*)(pw + col16 * 40 + rowg * 8);
      const bool dead = (c == 6) && (rowg >= 2);
      const int ko = dead ? 0 : c * 32 + rowg * 8;
#pragma unroll
      for (int dt = 0; dt < 4; ++dt) {
        bf16x8 vbv = *(const bf16x8*)(Vs + (dt * 16 + col16) * VS_ + ko);
        if (dead) { vbv = z8; }
        oa[dt] = __builtin_amdgcn_mfma_f32_16x16x32_bf16(pa, vbv, oa[dt], 0, 0, 0);
      }
    }

#pragma unroll
    for (int dt = 0; dt < 4; ++dt) {
#pragma unroll
      for (int r = 0; r < 4; ++r) {
        int qr = q0 + rowg * 4 + r;
        if (qr < 197)
          ob[((size_t)bb * 197 + qr) * 768 + hh * 64 + dt * 16 + col16] = f2bf(oa[dt][r]);
      }
    }
  }
}

// ------------------------------------------------------------- proj GEMM
__global__ __launch_bounds__(256) void k_gemm_proj(
    const u16* __restrict__ A, const u16* __restrict__ Bt,
    const float* __restrict__ bias, float* __restrict__ out) {
  __shared__ u16 SMEM[20480];               // 40960 B
  const int t = threadIdx.x, lane = t & 63;
  const int w = t >> 6;
  const int wr = (w >> 1) * 64, wc = (w & 1) * 64;
  const int wg = xcd_swz(blockIdx.x, 99 * 6);
  const int tm = wg / 6, tn = wg % 6;
  const int rowg = lane >> 4, col16 = lane & 15;

  f32x4 acc[4][4] = {};
  const u16* Abase = A + (size_t)tm * 128 * 768;
  const u16* Bbase = Bt + (size_t)tn * 128 * 768;

  GEMM_LOOP32(SMEM)

#pragma unroll
  for (int mi = 0; mi < 4; ++mi) {
#pragma unroll
    for (int r = 0; r < 4; ++r) {
      int gm = tm * 128 + wr + mi * 16 + rowg * 4 + r;
      if (gm >= M_) continue;
#pragma unroll
      for (int ni = 0; ni < 4; ++ni) {
        int gn = tn * 128 + wc + ni * 16 + col16;
        out[(size_t)gm * 768 + gn] = acc[mi][ni][r] + bias[gn];
      }
    }
  }
}

// ------------------------------------------------------------------ launch
extern "C" void kernel_launch(void* const* d_in, const int* in_sizes, int n_in,
                              void* d_out, int out_size, void* d_ws, size_t ws_size,
                              hipStream_t stream) {
  const float* x      = (const float*)d_in[0];
  const float* qkv_w  = (const float*)d_in[1];
  const float* qkv_b  = (const float*)d_in[2];
  const float* proj_w = (const float*)d_in[3];
  const float* proj_b = (const float*)d_in[4];
  const float* relpos = (const float*)d_in[5];
  const int*   rpidx  = (const int*)d_in[6];
  float* out = (float*)d_out;

  char* ws = (char*)d_ws;
  u16*   x16  = (u16*)(ws);                    // 19,464,192 B  [MPAD][768]
  u16*   wq16 = (u16*)(ws + 19464192);         //  3,538,944 B  [2304][768]
  u16*   wp16 = (u16*)(ws + 23003136);         //  1,179,648 B  [768][768]
  u16*   bb16 = (u16*)(ws + 24182784);         //    978,432 B  [12][196][208] bf16 (pre-scaled by log2e)
  u16*   q16  = (u16*)(ws + 25161216);         // 19,365,888 B  [B*H][197][64]
  u16*   k16  = (u16*)(ws + 44527104);         // 19,365,888 B  [B*H][197][64]
  u16*   vt16 = (u16*)(ws + 63892992);         // 22,020,096 B  [B*H][64][KP_]
  u16*   ao16 = (u16*)(ws + 85913088);         // 19,464,192 B  [MPAD][768]
  // total 105,377,280 B
  // vt16 pad keys (>=197) are never initialized: k_attn stages V into LDS
  // (keys 0..207 only) and zeroes keys 197..207 there; keys >=208 are never
  // read (dead-lane substitution in the PV loop).

  k_prep<<<7824, 256, 0, stream>>>(x, qkv_w, proj_w, relpos, rpidx,
                                   x16, wq16, wp16, bb16);
  k_gemm_qkv<<<99 * 18, 256, 0, stream>>>(x16, wq16, qkv_b, q16, k16, vt16);
  k_attn<<<768, 512, 0, stream>>>(q16, k16, vt16, bb16, ao16);
  k_gemm_proj<<<99 * 6, 256, 0, stream>>>(ao16, wp16, proj_b, out);
}

// Round 17
// 141.990 us; speedup vs baseline: 1.1065x; 1.1065x over previous
//
#include <hip/hip_runtime.h>
#include <hip/hip_bf16.h>
#include <stdint.h>

// Problem constants
#define B_    64
#define N_    197
#define C_    768
#define H_    12
#define HD_   64
#define M_    (B_ * N_)     // 12608
#define MPAD  12672         // 99 * 128
#define KP_   224           // padded key-dim stride for V^T (global)
#define VS_   208           // V^T row stride in LDS (26 granules -> <=2-way)
#define LOG2E 1.44269504f
#define QSCALE_ (0.125f * LOG2E)   // 64^-0.5 folded with log2e (softmax uses exp2)

typedef unsigned short u16;
typedef __attribute__((ext_vector_type(8))) __bf16 bf16x8;
typedef __attribute__((ext_vector_type(4))) float  f32x4;

__device__ __forceinline__ u16 f2bf(float f) {
  union { float f; uint32_t u; } v; v.f = f;
  uint32_t r = (v.u + 0x7FFFu + ((v.u >> 16) & 1u)) >> 16;
  return (u16)r;
}
__device__ __forceinline__ float bf2f(u16 u) {
  union { uint32_t u; float f; } v; v.u = ((uint32_t)u) << 16;
  return v.f;
}

// bijective XCD-chunked swizzle (m204): consecutive wgids land on one XCD.
__device__ __forceinline__ int xcd_swz(int orig, int nwg) {
  int q = nwg >> 3, r = nwg & 7;
  int xcd = orig & 7, idx = orig >> 3;
  int base = (xcd < r) ? xcd * (q + 1) : r * (q + 1) + (xcd - r) * q;
  return base + idx;
}

// async global->LDS 16B copy. Dest must be wave-base + lane*16 (linear).
#define GLDS(g, l)                                                             \
  __builtin_amdgcn_global_load_lds(                                            \
      (const __attribute__((address_space(1))) void*)(g),                      \
      (__attribute__((address_space(3))) void*)(l), 16, 0, 0)

// --------------------------------------------------------------- fused prep
__device__ __forceinline__ uint4 cvt8(const float* __restrict__ p) {
  const float4* s4 = (const float4*)p;
  float4 a = s4[0], b = s4[1];
  uint4 o;
  o.x = (uint32_t)f2bf(a.x) | ((uint32_t)f2bf(a.y) << 16);
  o.y = (uint32_t)f2bf(a.z) | ((uint32_t)f2bf(a.w) << 16);
  o.z = (uint32_t)f2bf(b.x) | ((uint32_t)f2bf(b.y) << 16);
  o.w = (uint32_t)f2bf(b.z) | ((uint32_t)f2bf(b.w) << 16);
  return o;
}

__global__ __launch_bounds__(256) void k_prep(
    const float* __restrict__ x, const float* __restrict__ qkv_w,
    const float* __restrict__ proj_w, const float* __restrict__ rel,
    const int* __restrict__ idx,
    u16* __restrict__ x16, u16* __restrict__ wq16, u16* __restrict__ wp16,
    u16* __restrict__ bb16) {
  const int b = blockIdx.x, t = threadIdx.x;
  if (b < 4752) {
    int i = b * 256 + t;
    size_t e = (size_t)i * 8;
    uint4 o;
    if (e < (size_t)M_ * C_) o = cvt8(x + e);
    else { o.x = o.y = o.z = o.w = 0u; }
    *(uint4*)(x16 + e) = o;
  } else if (b < 5616) {
    int i = (b - 4752) * 256 + t;
    if (i < 221184) { size_t e = (size_t)i * 8; *(uint4*)(wq16 + e) = cvt8(qkv_w + e); }
  } else if (b < 5904) {
    int i = (b - 5616) * 256 + t;
    if (i < 73728) { size_t e = (size_t)i * 8; *(uint4*)(wp16 + e) = cvt8(proj_w + e); }
  } else {
    int j = b - 5904;                 // 0..1919
    int h = j / 160;
    int i = (j - h * 160) * 256 + t;
    if (i < 196 * 208) {
      int qi1 = i / 208, colk = i - qi1 * 208;
      float v = 0.f;
      if (colk >= 1 && colk <= 196)
        v = rel[h * 729 + idx[qi1 * 196 + (colk - 1)]] * LOG2E;
      bb16[(size_t)h * 196 * 208 + i] = f2bf(v);
    }
  }
}

// ------------------------------------------------------------- qkv GEMM
// Proven 2-phase 128x128 BK=64 structure (R7/R14: ~74 us, 607 TF).
#define STAGE2(SM, buf, kt, Ab, Bb)                                            \
  do {                                                                         \
    u16* As_ = (SM) + (buf) * 16384;                                           \
    u16* Bs_ = As_ + 8192;                                                     \
    _Pragma("unroll") for (int r_ = 0; r_ < 4; ++r_) {                         \
      int c_ = r_ * 256 + t;                                                   \
      int row_ = c_ >> 3, sl_ = c_ & 7, p_ = sl_ ^ (row_ & 7);                 \
      GLDS((const char*)((Ab) + (size_t)row_ * 768 + (kt) * 64) + p_ * 16,     \
           (char*)As_ + c_ * 16);                                              \
      GLDS((const char*)((Bb) + (size_t)row_ * 768 + (kt) * 64) + p_ * 16,     \
           (char*)Bs_ + c_ * 16);                                              \
    }                                                                          \
  } while (0)

__global__ __launch_bounds__(256) void k_gemm_qkv(
    const u16* __restrict__ A, const u16* __restrict__ Bt,
    const float* __restrict__ bias,
    u16* __restrict__ qb, u16* __restrict__ kb, u16* __restrict__ vtb) {
  __shared__ u16 SMEM[32768];               // 64 KiB: 2 x (As 16K + Bs 16K)
  const int t = threadIdx.x, lane = t & 63;
  const int w = t >> 6;
  const int wr = (w >> 1) * 64, wc = (w & 1) * 64;
  const int wg = xcd_swz(blockIdx.x, 99 * 18);
  const int tm = wg / 18, tn = wg % 18;
  const int rowg = lane >> 4, col16 = lane & 15;

  f32x4 acc[4][4] = {};
  const u16* Abase = A + (size_t)tm * 128 * 768;
  const u16* Bbase = Bt + (size_t)tn * 128 * 768;

  STAGE2(SMEM, 0, 0, Abase, Bbase);
  __syncthreads();
  int cur = 0;
  for (int kt = 1; kt <= 12; ++kt) {
    if (kt < 12) STAGE2(SMEM, cur ^ 1, kt, Abase, Bbase);
    const u16* As_ = SMEM + cur * 16384;
    const u16* Bs_ = As_ + 8192;
#pragma unroll
    for (int kk = 0; kk < 2; ++kk) {
      bf16x8 af[4], bfr[4];
      int q = kk * 4 + rowg;
#pragma unroll
      for (int mi = 0; mi < 4; ++mi) {
        int row = wr + mi * 16 + col16;
        af[mi] = *(const bf16x8*)((const char*)As_ + row * 128 + ((q ^ (row & 7)) * 16));
      }
#pragma unroll
      for (int ni = 0; ni < 4; ++ni) {
        int row = wc + ni * 16 + col16;
        bfr[ni] = *(const bf16x8*)((const char*)Bs_ + row * 128 + ((q ^ (row & 7)) * 16));
      }
#pragma unroll
      for (int mi = 0; mi < 4; ++mi)
#pragma unroll
        for (int ni = 0; ni < 4; ++ni)
          acc[mi][ni] = __builtin_amdgcn_mfma_f32_16x16x32_bf16(af[mi], bfr[ni], acc[mi][ni], 0, 0, 0);
    }
    __syncthreads();
    cur ^= 1;
  }

  if (tn < 12) {
    u16* dst = (tn < 6) ? qb : kb;
    const float scl = (tn < 6) ? QSCALE_ : 1.f;
    const int colbase = tn * 128 - ((tn < 6) ? 0 : 768);
#pragma unroll
    for (int mi = 0; mi < 4; ++mi) {
#pragma unroll
      for (int r = 0; r < 4; ++r) {
        int gm = tm * 128 + wr + mi * 16 + rowg * 4 + r;
        if (gm >= M_) continue;
        int bb = gm / 197, nn = gm - bb * 197;
#pragma unroll
        for (int ni = 0; ni < 4; ++ni) {
          int n = wc + ni * 16 + col16;
          int rem = colbase + n;
          int hh = rem >> 6, hd = rem & 63;
          float v = (acc[mi][ni][r] + bias[tn * 128 + n]) * scl;
          dst[((size_t)(bb * 12 + hh) * 197 + nn) * 64 + hd] = f2bf(v);
        }
      }
    }
  } else {
    u16* T = SMEM;                          // [128][128] u16, XOR-swizzled
#pragma unroll
    for (int mi = 0; mi < 4; ++mi)
#pragma unroll
      for (int r = 0; r < 4; ++r) {
        int m = wr + mi * 16 + rowg * 4 + r;
#pragma unroll
        for (int ni = 0; ni < 4; ++ni) {
          int n = wc + ni * 16 + col16;
          float v = acc[mi][ni][r] + bias[tn * 128 + n];
          T[n * 128 + (m ^ ((n & 7) << 3))] = f2bf(v);
        }
      }
    __syncthreads();
    const int l = t & 15, g = t >> 4;
#pragma unroll
    for (int p = 0; p < 8; ++p) {
      int n = p * 16 + g;
      int rem = tn * 128 + n - 1536;
      int hh = rem >> 6, hd = rem & 63;
#pragma unroll
      for (int i = 0; i < 8; ++i) {
        int m = i * 16 + l;
        int gm = tm * 128 + m;
        if (gm >= M_) continue;
        int bb = gm / 197, nn = gm - bb * 197;
        u16 val = T[n * 128 + (m ^ ((n & 7) << 3))];
        vtb[((size_t)((bb * 12 + hh) * 64 + hd)) * KP_ + nn] = val;
      }
    }
  }
}

// ------------------------------------------------------------- attention
// R13 structure: one (b,h) per block, K/V staged once (62 KB LDS), 8 waves
// consume 13 q-tiles barrier-free.
__global__ __launch_bounds__(512) void k_attn(
    const u16* __restrict__ qb, const u16* __restrict__ kb,
    const u16* __restrict__ vtb, const u16* __restrict__ biasb,
    u16* __restrict__ ob) {
  __shared__ u16 Ks[208 * 64];              // 26.0 KB
  __shared__ u16 Vs[64 * VS_];              // 26.0 KB
  __shared__ u16 Ps[8][16 * 40];            // 10.0 KB   -> total 62 KB
  const int t = threadIdx.x, lane = t & 63, w = t >> 6;
  const int bh = xcd_swz(blockIdx.x, 768);
  const int hh = bh % 12, bb = bh / 12;
  const int rowg = lane >> 4, col16 = lane & 15;
  const u16* kbase = kb + (size_t)bh * 197 * 64;
  const u16* qbase = qb + (size_t)bh * 197 * 64;
  const u16* vbase = vtb + (size_t)bh * 64 * KP_;

#pragma unroll
  for (int i = 0; i < 4; ++i) {
    int c = i * 512 + t;
    if (c < 1664) {
      int row = c >> 3, sl = c & 7, p = sl ^ (row & 7);
      GLDS((const char*)(kbase + row * 64 + p * 8), (char*)Ks + c * 16);
    }
  }
#pragma unroll
  for (int i = 0; i < 4; ++i) {
    int c = i * 512 + t;
    if (c < 1664) {
      int vrow = c / 26, g = c - vrow * 26;
      GLDS((const char*)(vbase + vrow * 224 + g * 8), (char*)Vs + c * 16);
    }
  }
  asm volatile("s_waitcnt vmcnt(0)" ::: "memory");
  __syncthreads();
#pragma unroll
  for (int i = 0; i < 2; ++i) {
    int idx = i * 512 + t;
    if (idx < 704) {
      int r2 = idx / 11, e = idx - r2 * 11;
      Vs[r2 * VS_ + 197 + e] = 0;
    }
  }
  __syncthreads();

  for (int pass = 0; pass < 2; ++pass) {
    const int qt = w + pass * 8;
    if (qt > 12) break;
    const int q0 = qt * 16;
    const int qi = q0 + col16;

    bf16x8 qa0 = *(const bf16x8*)(qbase + (size_t)qi * 64 + rowg * 8);
    bf16x8 qa1 = *(const bf16x8*)(qbase + (size_t)qi * 64 + 32 + rowg * 8);

    const bool doB = (qi >= 1) && (qi < 197);
    const float bm = doB ? 1.f : 0.f;
    const u16* brow = biasb + ((size_t)hh * 196 + (doB ? qi - 1 : 0)) * 208;

    f32x4 sv[13];
    float mx = -1e38f;
#pragma unroll
    for (int nj = 0; nj < 13; ++nj) {
      int rk = nj * 16 + col16;
      const char* kp = (const char*)Ks + rk * 128;
      bf16x8 a0 = *(const bf16x8*)(kp + ((rowg ^ (rk & 7)) * 16));
      bf16x8 a1 = *(const bf16x8*)(kp + (((rowg + 4) ^ (rk & 7)) * 16));
      f32x4 s = {0.f, 0.f, 0.f, 0.f};
      s = __builtin_amdgcn_mfma_f32_16x16x32_bf16(a0, qa0, s, 0, 0, 0);
      s = __builtin_amdgcn_mfma_f32_16x16x32_bf16(a1, qa1, s, 0, 0, 0);
      ushort4 bu = *(const ushort4*)(brow + nj * 16 + rowg * 4);
      float s0 = fmaf(bf2f(bu.x), bm, s[0]);
      float s1 = fmaf(bf2f(bu.y), bm, s[1]);
      float s2 = fmaf(bf2f(bu.z), bm, s[2]);
      float s3 = fmaf(bf2f(bu.w), bm, s[3]);
      if (nj == 12) {
        if (192 + rowg * 4 + 0 >= 197) s0 = -1e38f;
        if (192 + rowg * 4 + 1 >= 197) s1 = -1e38f;
        if (192 + rowg * 4 + 2 >= 197) s2 = -1e38f;
        if (192 + rowg * 4 + 3 >= 197) s3 = -1e38f;
      }
      sv[nj][0] = s0; sv[nj][1] = s1; sv[nj][2] = s2; sv[nj][3] = s3;
      mx = fmaxf(fmaxf(mx, fmaxf(s0, s1)), fmaxf(s2, s3));
    }
    mx = fmaxf(mx, __shfl_xor(mx, 16));
    mx = fmaxf(mx, __shfl_xor(mx, 32));

    float sm = 0.f;
#pragma unroll
    for (int nj = 0; nj < 13; ++nj)
#pragma unroll
      for (int r = 0; r < 4; ++r) {
        float p = exp2f(sv[nj][r] - mx);
        sv[nj][r] = p;
        sm += p;
      }
    sm += __shfl_xor(sm, 16);
    sm += __shfl_xor(sm, 32);
    float inv = 1.f / sm;

    uint2 pk[13];
#pragma unroll
    for (int nj = 0; nj < 13; ++nj) {
      float n0 = sv[nj][0] * inv, n1 = sv[nj][1] * inv;
      float n2 = sv[nj][2] * inv, n3 = sv[nj][3] * inv;
      uint32_t lo, hi;
      asm("v_cvt_pk_bf16_f32 %0, %1, %2" : "=v"(lo) : "v"(n0), "v"(n1));
      asm("v_cvt_pk_bf16_f32 %0, %1, %2" : "=v"(hi) : "v"(n2), "v"(n3));
      pk[nj].x = lo; pk[nj].y = hi;
    }

    u16* pw = Ps[w];
    uint2 z2; z2.x = 0u; z2.y = 0u;
    union { uint32_t u[4]; bf16x8 v; } zz;
    zz.u[0] = zz.u[1] = zz.u[2] = zz.u[3] = 0u;
    const bf16x8 z8 = zz.v;

    f32x4 oa[4] = {};
#pragma unroll
    for (int c = 0; c < 7; ++c) {
      *(uint2*)(pw + col16 * 40 + rowg * 4) = pk[2 * c];
      *(uint2*)(pw + col16 * 40 + 16 + rowg * 4) = (c == 6) ? z2 : pk[2 * c + 1];
      bf16x8 pa = *(const bf16x8*)(pw + col16 * 40 + rowg * 8);
      const bool dead = (c == 6) && (rowg >= 2);
      const int ko = dead ? 0 : c * 32 + rowg * 8;
#pragma unroll
      for (int dt = 0; dt < 4; ++dt) {
        bf16x8 vbv = *(const bf16x8*)(Vs + (dt * 16 + col16) * VS_ + ko);
        if (dead) { vbv = z8; }
        oa[dt] = __builtin_amdgcn_mfma_f32_16x16x32_bf16(pa, vbv, oa[dt], 0, 0, 0);
      }
    }

#pragma unroll
    for (int dt = 0; dt < 4; ++dt) {
#pragma unroll
      for (int r = 0; r < 4; ++r) {
        int qr = q0 + rowg * 4 + r;
        if (qr < 197)
          ob[((size_t)bb * 197 + qr) * 768 + hh * 64 + dt * 16 + col16] = f2bf(oa[dt][r]);
      }
    }
  }
}

// ------------------------------------------------------------- proj GEMM
__global__ __launch_bounds__(256) void k_gemm_proj(
    const u16* __restrict__ A, const u16* __restrict__ Bt,
    const float* __restrict__ bias, float* __restrict__ out) {
  __shared__ u16 SMEM[32768];
  const int t = threadIdx.x, lane = t & 63;
  const int w = t >> 6;
  const int wr = (w >> 1) * 64, wc = (w & 1) * 64;
  const int wg = xcd_swz(blockIdx.x, 99 * 6);
  const int tm = wg / 6, tn = wg % 6;
  const int rowg = lane >> 4, col16 = lane & 15;

  f32x4 acc[4][4] = {};
  const u16* Abase = A + (size_t)tm * 128 * 768;
  const u16* Bbase = Bt + (size_t)tn * 128 * 768;

  STAGE2(SMEM, 0, 0, Abase, Bbase);
  __syncthreads();
  int cur = 0;
  for (int kt = 1; kt <= 12; ++kt) {
    if (kt < 12) STAGE2(SMEM, cur ^ 1, kt, Abase, Bbase);
    const u16* As_ = SMEM + cur * 16384;
    const u16* Bs_ = As_ + 8192;
#pragma unroll
    for (int kk = 0; kk < 2; ++kk) {
      bf16x8 af[4], bfr[4];
      int q = kk * 4 + rowg;
#pragma unroll
      for (int mi = 0; mi < 4; ++mi) {
        int row = wr + mi * 16 + col16;
        af[mi] = *(const bf16x8*)((const char*)As_ + row * 128 + ((q ^ (row & 7)) * 16));
      }
#pragma unroll
      for (int ni = 0; ni < 4; ++ni) {
        int row = wc + ni * 16 + col16;
        bfr[ni] = *(const bf16x8*)((const char*)Bs_ + row * 128 + ((q ^ (row & 7)) * 16));
      }
#pragma unroll
      for (int mi = 0; mi < 4; ++mi)
#pragma unroll
        for (int ni = 0; ni < 4; ++ni)
          acc[mi][ni] = __builtin_amdgcn_mfma_f32_16x16x32_bf16(af[mi], bfr[ni], acc[mi][ni], 0, 0, 0);
    }
    __syncthreads();
    cur ^= 1;
  }

#pragma unroll
  for (int mi = 0; mi < 4; ++mi) {
#pragma unroll
    for (int r = 0; r < 4; ++r) {
      int gm = tm * 128 + wr + mi * 16 + rowg * 4 + r;
      if (gm >= M_) continue;
#pragma unroll
      for (int ni = 0; ni < 4; ++ni) {
        int gn = tn * 128 + wc + ni * 16 + col16;
        out[(size_t)gm * 768 + gn] = acc[mi][ni][r] + bias[gn];
      }
    }
  }
}

// ------------------------------------------------------------------ launch
extern "C" void kernel_launch(void* const* d_in, const int* in_sizes, int n_in,
                              void* d_out, int out_size, void* d_ws, size_t ws_size,
                              hipStream_t stream) {
  const float* x      = (const float*)d_in[0];
  const float* qkv_w  = (const float*)d_in[1];
  const float* qkv_b  = (const float*)d_in[2];
  const float* proj_w = (const float*)d_in[3];
  const float* proj_b = (const float*)d_in[4];
  const float* relpos = (const float*)d_in[5];
  const int*   rpidx  = (const int*)d_in[6];
  float* out = (float*)d_out;

  char* ws = (char*)d_ws;
  u16*   x16  = (u16*)(ws);                    // 19,464,192 B  [MPAD][768]
  u16*   wq16 = (u16*)(ws + 19464192);         //  3,538,944 B  [2304][768]
  u16*   wp16 = (u16*)(ws + 23003136);         //  1,179,648 B  [768][768]
  u16*   bb16 = (u16*)(ws + 24182784);         //    978,432 B  [12][196][208] bf16 (pre-scaled by log2e)
  u16*   q16  = (u16*)(ws + 25161216);         // 19,365,888 B  [B*H][197][64]
  u16*   k16  = (u16*)(ws + 44527104);         // 19,365,888 B  [B*H][197][64]
  u16*   vt16 = (u16*)(ws + 63892992);         // 22,020,096 B  [B*H][64][KP_]
  u16*   ao16 = (u16*)(ws + 85913088);         // 19,464,192 B  [MPAD][768]
  // total 105,377,280 B
  // vt16 pad keys (>=197) are never initialized: k_attn stages V into LDS
  // (keys 0..207 only) and zeroes keys 197..207 there; keys >=208 are never
  // read (dead-lane substitution in the PV loop).

  k_prep<<<7824, 256, 0, stream>>>(x, qkv_w, proj_w, relpos, rpidx,
                                   x16, wq16, wp16, bb16);
  k_gemm_qkv<<<99 * 18, 256, 0, stream>>>(x16, wq16, qkv_b, q16, k16, vt16);
  k_attn<<<768, 512, 0, stream>>>(q16, k16, vt16, bb16, ao16);
  k_gemm_proj<<<99 * 6, 256, 0, stream>>>(ao16, wp16, proj_b, out);
}